// Round 10
// baseline (354.450 us; speedup 1.0000x reference)
//
#include <hip/hip_runtime.h>
#include <hip/hip_bf16.h>
#include <hip/hip_fp16.h>

// Pipeline:
//  x (4,64,130,130) --conv3x3 valid + bias + maxpool2x2--> p1 (4,64,64,64)
//  p1 --1x1 conv (64->32)--> t2 (4,32,64,64)
//  t2 --3x3 conv pad=1 (32->32)--> t3 (4,32,64,64)
//  t3 --1x1 conv (32->1152)--> t4h[b][strip][chunk][ckk][16 po]  fp16 (oy,ox)
//  deform_conv(x, upsample2x(offsets), wd) -> out (4,64,128,128)
//  Deform: offsets at half res => 2x2 quad shares (fy,fx); 16 bilinear taps
//  collapse to a 3x3 grid. Block = (16-po strip) x (half of input channels):
//  grid 2048 = 8 blocks/CU = 32 waves/CU (c-split for occupancy). Single-chunk
//  vlds = 18.7 KB. Halves write partial buffers; k_add combines (no atomics).

#define HX 130
#define WX 130

// ---------------- K0: wd (o,c,3,3) -> wdt2[(c*9+k)*64 + o]  (k-major)
__global__ __launch_bounds__(256) void k_wdt(const float* __restrict__ wd,
                                             float* __restrict__ wdt2) {
    int idx = blockIdx.x * 256 + threadIdx.x;   // 64*64*9 = 36864
    if (idx >= 36864) return;
    int k = idx % 9;
    int rem = idx / 9;        // o*64 + c
    int c = rem & 63;
    int o = rem >> 6;
    wdt2[(c * 9 + k) * 64 + o] = wd[idx];
}

// ---------------- K1: conv3x3 valid (64->64) + bias + maxpool 2x2 -> p1
// grid 1024 = b(4) * cog(16, 4 oc) * tile(16, 4 pooled rows); block 256
__global__ __launch_bounds__(256, 4) void k_conv0_pool(const float* __restrict__ x,
                                                       const float* __restrict__ w0,
                                                       const float* __restrict__ b0,
                                                       float* __restrict__ p1) {
    int idx = blockIdx.x;
    int tile = idx & 15;          // 4 pooled rows each
    int cog = (idx >> 4) & 15;    // blockIdx-derived -> weight loads scalar
    int b = idx >> 8;
    int tid = threadIdx.x;
    int pw = tid & 63;
    int phl = tid >> 6;           // 0..3
    int ph = tile * 4 + phl;
    __shared__ float slab[2][10 * WX];        // 2 ci x 1300 floats
    const float* xb = x + (size_t)(b * 64) * HX * WX;
    int row0 = tile * 8;          // x rows row0..row0+9
    const float* xbase = xb + row0 * WX;
    float acc[4][4];
    #pragma unroll
    for (int i = 0; i < 4; ++i)
        #pragma unroll
        for (int j = 0; j < 4; ++j) acc[i][j] = 0.f;

    float pre[11];
    #pragma unroll
    for (int j = 0; j < 11; ++j) {
        int i = tid + j * 256;    // 0..2599 covers both ci slabs
        int ci = i / 1300, off = i - ci * 1300;
        pre[j] = (i < 2600) ? xbase[(size_t)ci * (HX * WX) + off] : 0.f;
    }

    for (int cg = 0; cg < 32; ++cg) {         // 2 ci per stage
        __syncthreads();
        #pragma unroll
        for (int j = 0; j < 11; ++j) {
            int i = tid + j * 256;
            if (i < 2600) ((float*)slab)[i] = pre[j];
        }
        __syncthreads();
        if (cg < 31) {
            const float* xp = xbase + (size_t)(2 * cg + 2) * (HX * WX);
            #pragma unroll
            for (int j = 0; j < 11; ++j) {
                int i = tid + j * 256;
                int ci = i / 1300, off = i - ci * 1300;
                pre[j] = (i < 2600) ? xp[(size_t)ci * (HX * WX) + off] : 0.f;
            }
        }
        #pragma unroll
        for (int lc = 0; lc < 2; ++lc) {
            int ci = 2 * cg + lc;
            float v[4][4];
            #pragma unroll
            for (int r2 = 0; r2 < 4; ++r2) {
                const float* rp = &slab[lc][(2 * phl + r2) * WX + 2 * pw];
                float2 a = *(const float2*)rp;
                float2 bb = *(const float2*)(rp + 2);
                v[r2][0] = a.x; v[r2][1] = a.y; v[r2][2] = bb.x; v[r2][3] = bb.y;
            }
            #pragma unroll
            for (int i = 0; i < 4; ++i) {
                const float* wp = w0 + (((cog * 4 + i) * 64) + ci) * 9;  // uniform
                float w[9];
                #pragma unroll
                for (int k = 0; k < 9; ++k) w[k] = wp[k];
                #pragma unroll
                for (int dr = 0; dr < 2; ++dr)
                    #pragma unroll
                    for (int dc = 0; dc < 2; ++dc) {
                        float s = acc[i][dr * 2 + dc];
                        #pragma unroll
                        for (int ky = 0; ky < 3; ++ky)
                            #pragma unroll
                            for (int kx = 0; kx < 3; ++kx)
                                s += w[ky * 3 + kx] * v[dr + ky][dc + kx];
                        acc[i][dr * 2 + dc] = s;
                    }
            }
        }
    }
    #pragma unroll
    for (int i = 0; i < 4; ++i) {
        float m = fmaxf(fmaxf(acc[i][0], acc[i][1]), fmaxf(acc[i][2], acc[i][3]))
                + b0[cog * 4 + i];
        p1[(((size_t)b * 64 + cog * 4 + i) * 64 + ph) * 64 + pw] = m;
    }
}

// ---------------- K2: 1x1 conv 64->32 on 64x64; grid 1024 (2 oc/thread)
__global__ __launch_bounds__(256) void k_conv1x1_a(const float* __restrict__ p1,
                                                   const float* __restrict__ w1,
                                                   const float* __restrict__ b1,
                                                   float* __restrict__ t2) {
    int blk = blockIdx.x;
    int pt = blk & 15;
    int cog = (blk >> 4) & 15;
    int b = blk >> 8;
    int p = pt * 256 + threadIdx.x;
    float acc[2];
    #pragma unroll
    for (int i = 0; i < 2; ++i) acc[i] = b1[cog * 2 + i];
    const float* ip = p1 + (size_t)b * 64 * 4096 + p;
    for (int ci = 0; ci < 64; ++ci) {
        float v = ip[(size_t)ci * 4096];
        #pragma unroll
        for (int i = 0; i < 2; ++i) acc[i] += w1[(cog * 2 + i) * 64 + ci] * v;
    }
    float* op = t2 + (size_t)b * 32 * 4096 + p;
    #pragma unroll
    for (int i = 0; i < 2; ++i) op[(size_t)(cog * 2 + i) * 4096] = acc[i];
}

// ---------------- K3: 3x3 conv pad=1, 32->32 on 64x64; grid 1024 (2 oc/thread)
__global__ __launch_bounds__(256) void k_conv3x3_b(const float* __restrict__ t2,
                                                   const float* __restrict__ w2,
                                                   const float* __restrict__ b2,
                                                   float* __restrict__ t3) {
    int blk = blockIdx.x;
    int pt = blk & 15;
    int cog = (blk >> 4) & 15;
    int b = blk >> 8;
    int p = pt * 256 + threadIdx.x;
    int hy = p >> 6, wx = p & 63;
    float acc[2];
    #pragma unroll
    for (int i = 0; i < 2; ++i) acc[i] = b2[cog * 2 + i];
    const float* ip = t2 + (size_t)b * 32 * 4096;
    for (int ci = 0; ci < 32; ++ci) {
        float v[9];
        #pragma unroll
        for (int ky = 0; ky < 3; ++ky) {
            int yy = hy + ky - 1;
            #pragma unroll
            for (int kx = 0; kx < 3; ++kx) {
                int xx = wx + kx - 1;
                bool ok = (yy >= 0 && yy < 64 && xx >= 0 && xx < 64);
                int yc = min(max(yy, 0), 63), xc = min(max(xx, 0), 63);
                float val = ip[(size_t)ci * 4096 + yc * 64 + xc];
                v[ky * 3 + kx] = ok ? val : 0.f;
            }
        }
        #pragma unroll
        for (int i = 0; i < 2; ++i) {
            const float* wp = w2 + (((cog * 2 + i) * 32) + ci) * 9;   // uniform
            float s = acc[i];
            #pragma unroll
            for (int k = 0; k < 9; ++k) s += wp[k] * v[k];
            acc[i] = s;
        }
    }
    float* op = t3 + (size_t)b * 32 * 4096 + p;
    #pragma unroll
    for (int i = 0; i < 2; ++i) op[(size_t)(cog * 2 + i) * 4096] = acc[i];
}

// ---------------- K4: 1x1 conv 32->1152 -> fp16 (oy,ox)-paired strip-blocked
// t4h[b][strip][chunk(8)][ckk(72)][po(16)] as __half2.  grid 4608.
__global__ __launch_bounds__(256) void k_conv1x1_off(const float* __restrict__ t3,
                                                     const float* __restrict__ w3,
                                                     const float* __restrict__ b3,
                                                     __half2* __restrict__ t4h) {
    int blk = blockIdx.x;
    int pt = blk & 15;
    int rem = blk >> 4;           // 0..287
    int chg = rem % 72;           // blockIdx-derived -> scalar weight loads
    int b = rem / 72;
    int p = pt * 256 + threadIdx.x;
    float v[32];
    const float* ip = t3 + (size_t)b * 32 * 4096 + p;
    #pragma unroll
    for (int ci = 0; ci < 32; ++ci) v[ci] = ip[(size_t)ci * 4096];
    int strip = p >> 4, pl = p & 15;
    __half2* base = t4h + (size_t)(b * 256 + strip) * 9216;   // 8*1152 half2
    #pragma unroll
    for (int m = 0; m < 8; ++m) {
        int chE = chg * 16 + 2 * m;
        float accE = b3[chE], accO = b3[chE + 1];
        const float* wpE = w3 + chE * 32;         // uniform
        const float* wpO = wpE + 32;
        #pragma unroll
        for (int ci = 0; ci < 32; ++ci) {
            accE += wpE[ci] * v[ci];
            accO += wpO[ci] * v[ci];
        }
        int gp = chg * 8 + m;                     // global pair 0..575
        int chunk = gp / 72;
        int ckk = gp - chunk * 72;
        base[chunk * 1152 + ckk * 16 + pl] = __floats2half2_rn(accE, accO);
    }
}

// ---------------- K5: deformable conv, c-split across blocks for occupancy
// grid 2048 = half(2) x strip(256) x b(4): blk = (half<<10) | (strip<<2) | b
// block 256: og = tid>>4 (16 groups of 4 oc), q = tid&15. Each block does
// chunks half*4..half*4+3 (32 input ch), single-chunk vlds (18688 B) ->
// 8 blocks/CU = 32 waves/CU. Writes partials; k_add combines.
#define VP 292   // vlds quad pitch in floats (72*4 + 4)
__global__ __launch_bounds__(256, 8) void k_deform(const float* __restrict__ x,
                                                   const __half2* __restrict__ t4h,
                                                   const float* __restrict__ wdt2,
                                                   float* __restrict__ pout) {
    int blk = blockIdx.x;
    int b = blk & 3;
    int strip = (blk >> 2) & 255;
    int half = blk >> 10;
    int tid = threadIdx.x;
    int og = tid >> 4;            // 0..15 (4 out-channels each)
    int q = tid & 15;             // quad in strip
    int po0 = strip * 16;
    int qy = po0 >> 6;            // strip lies in one quad-row
    int qx0 = po0 & 63;

    __shared__ __align__(16) float vlds[16 * VP];  // 18688 B

    float acc[4][4];
    #pragma unroll
    for (int o = 0; o < 4; ++o)
        #pragma unroll
        for (int s = 0; s < 4; ++s) acc[o][s] = 0.f;

    const float* xb = x + (size_t)b * 64 * HX * WX;
    const __half2* osrc = t4h + (size_t)(b * 256 + strip) * 9216 + half * 4608;

    for (int st = 0; st < 4; ++st) {
        int chunk = half * 4 + st;
        __syncthreads();          // prev phase2 done with vlds
        // hoisted offset loads: 1152 half2 = 4 full iters + 128 tail; coalesced
        __half2 o2h[5];
        #pragma unroll
        for (int it = 0; it < 5; ++it) {
            int i2 = it * 256 + tid;
            if (it < 4 || tid < 128) o2h[it] = osrc[st * 1152 + i2];
        }
        // ---- phase 1: 1152 tasks (16 q x 72 ckk)
        #pragma unroll
        for (int it = 0; it < 5; ++it) {
            if (it < 4 || tid < 128) {
                int idx = it * 256 + tid;     // 0..1151
                int ckk = idx >> 4;           // 0..71 = ch*9+kk
                int tq = idx & 15;
                int ch = (ckk * 57) >> 9;     // /9
                int kk = ckk - ch * 9;
                int c = chunk * 8 + ch;
                float2 off = __half22float2(o2h[it]);
                float py = off.x + (float)(2 * qy + kk / 3);
                float px = off.y + (float)(2 * (qx0 + tq) + kk % 3);
                float y0f = floorf(py), x0f = floorf(px);
                float fy = py - y0f, fx = px - x0f;
                int y0 = (int)y0f, x0 = (int)x0f;
                const float* xp = xb + (size_t)c * (HX * WX);
                float t[3][3];
                #pragma unroll
                for (int r = 0; r < 3; ++r) {
                    int yy = y0 + r;
                    bool vy = (yy >= 0) & (yy < HX);
                    int yc = min(max(yy, 0), HX - 1);
                    #pragma unroll
                    for (int sx = 0; sx < 3; ++sx) {
                        int xx = x0 + sx;
                        bool vx = (xx >= 0) & (xx < WX);
                        int xc = min(max(xx, 0), WX - 1);
                        float val = xp[yc * WX + xc];
                        t[r][sx] = (vy & vx) ? val : 0.f;
                    }
                }
                float h0[3], h1[3];
                #pragma unroll
                for (int r = 0; r < 3; ++r) {
                    h0[r] = t[r][0] + fx * (t[r][1] - t[r][0]);
                    h1[r] = t[r][1] + fx * (t[r][2] - t[r][1]);
                }
                float4 vv;
                vv.x = h0[0] + fy * (h0[1] - h0[0]);   // sub (0,0)
                vv.y = h1[0] + fy * (h1[1] - h1[0]);   // sub (0,1)
                vv.z = h0[1] + fy * (h0[2] - h0[1]);   // sub (1,0)
                vv.w = h1[1] + fy * (h1[2] - h1[1]);   // sub (1,1)
                *(float4*)&vlds[tq * VP + ckk * 4] = vv;
            }
        }
        __syncthreads();          // vlds visible

        // ---- phase 2: acc[4 outs][4 sub] += w * v  (16 FMA per b128 read)
        for (int ch = 0; ch < 8; ++ch) {
            int c = chunk * 8 + ch;
            const float* wp = wdt2 + (size_t)(c * 9) * 64 + og * 4;
            const float* vp = &vlds[q * VP + (ch * 9) * 4];
            #pragma unroll
            for (int k = 0; k < 9; ++k) {
                float4 vv = *(const float4*)(vp + k * 4);
                float4 w4 = *(const float4*)(wp + k * 64);
                float wv[4] = {w4.x, w4.y, w4.z, w4.w};
                #pragma unroll
                for (int o = 0; o < 4; ++o) {
                    acc[o][0] += wv[o] * vv.x;
                    acc[o][1] += wv[o] * vv.y;
                    acc[o][2] += wv[o] * vv.z;
                    acc[o][3] += wv[o] * vv.w;
                }
            }
        }
    }
    // ---- epilogue: plain coalesced stores to this half's partial buffer
    float* outh = pout + (size_t)half * 4194304;
    int ho = 2 * qy, wo = 2 * (qx0 + q);
    #pragma unroll
    for (int o = 0; o < 4; ++o) {
        int oc = og * 4 + o;
        float* op = outh + (((size_t)b * 64 + oc) * 128 + ho) * 128 + wo;
        *(float2*)op = make_float2(acc[o][0], acc[o][1]);
        *(float2*)(op + 128) = make_float2(acc[o][2], acc[o][3]);
    }
}

// ---------------- K6: out = pa + pb (combine c-split halves); grid 4096
__global__ __launch_bounds__(256) void k_add(const float* __restrict__ pa,
                                             const float* __restrict__ pb,
                                             float* __restrict__ out) {
    int i = (blockIdx.x * 256 + threadIdx.x) * 4;   // 4,194,304 floats total
    float4 a = *(const float4*)(pa + i);
    float4 b = *(const float4*)(pb + i);
    *(float4*)(out + i) = make_float4(a.x + b.x, a.y + b.y, a.z + b.z, a.w + b.w);
}

extern "C" void kernel_launch(void* const* d_in, const int* in_sizes, int n_in,
                              void* d_out, int out_size, void* d_ws, size_t ws_size,
                              hipStream_t stream) {
    const float* x  = (const float*)d_in[0];
    const float* w0 = (const float*)d_in[1];
    const float* b0 = (const float*)d_in[2];
    const float* w1 = (const float*)d_in[3];
    const float* b1 = (const float*)d_in[4];
    const float* w2 = (const float*)d_in[5];
    const float* b2 = (const float*)d_in[6];
    const float* w3 = (const float*)d_in[7];
    const float* b3 = (const float*)d_in[8];
    const float* wd = (const float*)d_in[9];
    float* out = (float*)d_out;

    float* ws = (float*)d_ws;
    float* p1    = ws;                       // 1,048,576 floats
    float* t2    = p1 + 1048576;             //   524,288
    float* t3    = t2 + 524288;              //   524,288
    __half2* t4h = (__half2*)(t3 + 524288);  // 9,437,184 half2 (37.7 MB)
    float* wdt2  = (float*)(t4h + 9437184);  //    36,864 floats
    float* pout  = wdt2 + 36864;             // 2 x 4,194,304 floats (33.5 MB)

    k_wdt<<<144, 256, 0, stream>>>(wd, wdt2);
    k_conv0_pool<<<1024, 256, 0, stream>>>(x, w0, b0, p1);
    k_conv1x1_a<<<1024, 256, 0, stream>>>(p1, w1, b1, t2);
    k_conv3x3_b<<<1024, 256, 0, stream>>>(t2, w2, b2, t3);
    k_conv1x1_off<<<4608, 256, 0, stream>>>(t3, w3, b3, t4h);
    k_deform<<<2048, 256, 0, stream>>>(x, t4h, wdt2, pout);
    k_add<<<4096, 256, 0, stream>>>(pout, pout + 4194304, out);
}

// Round 11
// 329.289 us; speedup vs baseline: 1.0764x; 1.0764x over previous
//
#include <hip/hip_runtime.h>
#include <hip/hip_bf16.h>
#include <hip/hip_fp16.h>

// Pipeline:
//  x (4,64,130,130) --conv3x3 valid + bias + maxpool2x2--> p1 (4,64,64,64)
//  p1 --1x1 conv (64->32)--> t2 (4,32,64,64)
//  t2 --3x3 conv pad=1 (32->32)--> t3 (4,32,64,64)
//  t3 --1x1 conv (32->1152)--> t4h[b][strip][chunk][ckk][16 po]  fp16 (oy,ox)
//  deform_conv(x, upsample2x(offsets), wd) -> out (4,64,128,128)
//  Deform: offsets at half res => 2x2 quad shares (fy,fx); 16 bilinear taps
//  collapse to a 3x3 grid. Block = 16-po strip, 4 blocks/CU (R9 operating
//  point: minimal HBM traffic). Phase-1 gathers batched 3 tasks deep (27
//  outstanding loads/thread) for memory-level parallelism.

#define HX 130
#define WX 130

// ---------------- K0: wd (o,c,3,3) -> wdt2[(c*9+k)*64 + o]  (k-major)
__global__ __launch_bounds__(256) void k_wdt(const float* __restrict__ wd,
                                             float* __restrict__ wdt2) {
    int idx = blockIdx.x * 256 + threadIdx.x;   // 64*64*9 = 36864
    if (idx >= 36864) return;
    int k = idx % 9;
    int rem = idx / 9;        // o*64 + c
    int c = rem & 63;
    int o = rem >> 6;
    wdt2[(c * 9 + k) * 64 + o] = wd[idx];
}

// ---------------- K1: conv3x3 valid (64->64) + bias + maxpool 2x2 -> p1
// grid 1024 = b(4) * cog(16, 4 oc) * tile(16, 4 pooled rows); block 256
__global__ __launch_bounds__(256, 4) void k_conv0_pool(const float* __restrict__ x,
                                                       const float* __restrict__ w0,
                                                       const float* __restrict__ b0,
                                                       float* __restrict__ p1) {
    int idx = blockIdx.x;
    int tile = idx & 15;          // 4 pooled rows each
    int cog = (idx >> 4) & 15;    // blockIdx-derived -> weight loads scalar
    int b = idx >> 8;
    int tid = threadIdx.x;
    int pw = tid & 63;
    int phl = tid >> 6;           // 0..3
    int ph = tile * 4 + phl;
    __shared__ float slab[2][10 * WX];        // 2 ci x 1300 floats
    const float* xb = x + (size_t)(b * 64) * HX * WX;
    int row0 = tile * 8;          // x rows row0..row0+9
    const float* xbase = xb + row0 * WX;
    float acc[4][4];
    #pragma unroll
    for (int i = 0; i < 4; ++i)
        #pragma unroll
        for (int j = 0; j < 4; ++j) acc[i][j] = 0.f;

    float pre[11];
    #pragma unroll
    for (int j = 0; j < 11; ++j) {
        int i = tid + j * 256;    // 0..2599 covers both ci slabs
        int ci = i / 1300, off = i - ci * 1300;
        pre[j] = (i < 2600) ? xbase[(size_t)ci * (HX * WX) + off] : 0.f;
    }

    for (int cg = 0; cg < 32; ++cg) {         // 2 ci per stage
        __syncthreads();
        #pragma unroll
        for (int j = 0; j < 11; ++j) {
            int i = tid + j * 256;
            if (i < 2600) ((float*)slab)[i] = pre[j];
        }
        __syncthreads();
        if (cg < 31) {
            const float* xp = xbase + (size_t)(2 * cg + 2) * (HX * WX);
            #pragma unroll
            for (int j = 0; j < 11; ++j) {
                int i = tid + j * 256;
                int ci = i / 1300, off = i - ci * 1300;
                pre[j] = (i < 2600) ? xp[(size_t)ci * (HX * WX) + off] : 0.f;
            }
        }
        #pragma unroll
        for (int lc = 0; lc < 2; ++lc) {
            int ci = 2 * cg + lc;
            float v[4][4];
            #pragma unroll
            for (int r2 = 0; r2 < 4; ++r2) {
                const float* rp = &slab[lc][(2 * phl + r2) * WX + 2 * pw];
                float2 a = *(const float2*)rp;
                float2 bb = *(const float2*)(rp + 2);
                v[r2][0] = a.x; v[r2][1] = a.y; v[r2][2] = bb.x; v[r2][3] = bb.y;
            }
            #pragma unroll
            for (int i = 0; i < 4; ++i) {
                const float* wp = w0 + (((cog * 4 + i) * 64) + ci) * 9;  // uniform
                float w[9];
                #pragma unroll
                for (int k = 0; k < 9; ++k) w[k] = wp[k];
                #pragma unroll
                for (int dr = 0; dr < 2; ++dr)
                    #pragma unroll
                    for (int dc = 0; dc < 2; ++dc) {
                        float s = acc[i][dr * 2 + dc];
                        #pragma unroll
                        for (int ky = 0; ky < 3; ++ky)
                            #pragma unroll
                            for (int kx = 0; kx < 3; ++kx)
                                s += w[ky * 3 + kx] * v[dr + ky][dc + kx];
                        acc[i][dr * 2 + dc] = s;
                    }
            }
        }
    }
    #pragma unroll
    for (int i = 0; i < 4; ++i) {
        float m = fmaxf(fmaxf(acc[i][0], acc[i][1]), fmaxf(acc[i][2], acc[i][3]))
                + b0[cog * 4 + i];
        p1[(((size_t)b * 64 + cog * 4 + i) * 64 + ph) * 64 + pw] = m;
    }
}

// ---------------- K2: 1x1 conv 64->32 on 64x64; grid 1024 (2 oc/thread)
__global__ __launch_bounds__(256) void k_conv1x1_a(const float* __restrict__ p1,
                                                   const float* __restrict__ w1,
                                                   const float* __restrict__ b1,
                                                   float* __restrict__ t2) {
    int blk = blockIdx.x;
    int pt = blk & 15;
    int cog = (blk >> 4) & 15;
    int b = blk >> 8;
    int p = pt * 256 + threadIdx.x;
    float acc[2];
    #pragma unroll
    for (int i = 0; i < 2; ++i) acc[i] = b1[cog * 2 + i];
    const float* ip = p1 + (size_t)b * 64 * 4096 + p;
    for (int ci = 0; ci < 64; ++ci) {
        float v = ip[(size_t)ci * 4096];
        #pragma unroll
        for (int i = 0; i < 2; ++i) acc[i] += w1[(cog * 2 + i) * 64 + ci] * v;
    }
    float* op = t2 + (size_t)b * 32 * 4096 + p;
    #pragma unroll
    for (int i = 0; i < 2; ++i) op[(size_t)(cog * 2 + i) * 4096] = acc[i];
}

// ---------------- K3: 3x3 conv pad=1, 32->32 on 64x64; grid 1024 (2 oc/thread)
__global__ __launch_bounds__(256) void k_conv3x3_b(const float* __restrict__ t2,
                                                   const float* __restrict__ w2,
                                                   const float* __restrict__ b2,
                                                   float* __restrict__ t3) {
    int blk = blockIdx.x;
    int pt = blk & 15;
    int cog = (blk >> 4) & 15;
    int b = blk >> 8;
    int p = pt * 256 + threadIdx.x;
    int hy = p >> 6, wx = p & 63;
    float acc[2];
    #pragma unroll
    for (int i = 0; i < 2; ++i) acc[i] = b2[cog * 2 + i];
    const float* ip = t2 + (size_t)b * 32 * 4096;
    for (int ci = 0; ci < 32; ++ci) {
        float v[9];
        #pragma unroll
        for (int ky = 0; ky < 3; ++ky) {
            int yy = hy + ky - 1;
            #pragma unroll
            for (int kx = 0; kx < 3; ++kx) {
                int xx = wx + kx - 1;
                bool ok = (yy >= 0 && yy < 64 && xx >= 0 && xx < 64);
                int yc = min(max(yy, 0), 63), xc = min(max(xx, 0), 63);
                float val = ip[(size_t)ci * 4096 + yc * 64 + xc];
                v[ky * 3 + kx] = ok ? val : 0.f;
            }
        }
        #pragma unroll
        for (int i = 0; i < 2; ++i) {
            const float* wp = w2 + (((cog * 2 + i) * 32) + ci) * 9;   // uniform
            float s = acc[i];
            #pragma unroll
            for (int k = 0; k < 9; ++k) s += wp[k] * v[k];
            acc[i] = s;
        }
    }
    float* op = t3 + (size_t)b * 32 * 4096 + p;
    #pragma unroll
    for (int i = 0; i < 2; ++i) op[(size_t)(cog * 2 + i) * 4096] = acc[i];
}

// ---------------- K4: 1x1 conv 32->1152 -> fp16 (oy,ox)-paired strip-blocked
// t4h[b][strip][chunk(8)][ckk(72)][po(16)] as __half2.  grid 4608.
__global__ __launch_bounds__(256) void k_conv1x1_off(const float* __restrict__ t3,
                                                     const float* __restrict__ w3,
                                                     const float* __restrict__ b3,
                                                     __half2* __restrict__ t4h) {
    int blk = blockIdx.x;
    int pt = blk & 15;
    int rem = blk >> 4;           // 0..287
    int chg = rem % 72;           // blockIdx-derived -> scalar weight loads
    int b = rem / 72;
    int p = pt * 256 + threadIdx.x;
    float v[32];
    const float* ip = t3 + (size_t)b * 32 * 4096 + p;
    #pragma unroll
    for (int ci = 0; ci < 32; ++ci) v[ci] = ip[(size_t)ci * 4096];
    int strip = p >> 4, pl = p & 15;
    __half2* base = t4h + (size_t)(b * 256 + strip) * 9216;   // 8*1152 half2
    #pragma unroll
    for (int m = 0; m < 8; ++m) {
        int chE = chg * 16 + 2 * m;
        float accE = b3[chE], accO = b3[chE + 1];
        const float* wpE = w3 + chE * 32;         // uniform
        const float* wpO = wpE + 32;
        #pragma unroll
        for (int ci = 0; ci < 32; ++ci) {
            accE += wpE[ci] * v[ci];
            accO += wpO[ci] * v[ci];
        }
        int gp = chg * 8 + m;                     // global pair 0..575
        int chunk = gp / 72;
        int ckk = gp - chunk * 72;
        base[chunk * 1152 + ckk * 16 + pl] = __floats2half2_rn(accE, accO);
    }
}

// ---------------- K5: deformable conv (R9 structure + batched phase-1 MLP)
// grid 1024 = strip(256)*4 + b  [blk&7 = b + 4*(strip&1) -> XCD sees one batch]
// block 256: og = tid>>4 (16 groups of 4 oc), q = tid&15 (quad in strip).
// 2 chunks per barrier; phase-1 tasks batched 3-deep: 27 outstanding gathers.
#define VP 292   // vlds quad pitch in floats (72*4 + 4)
__global__ __launch_bounds__(256, 4) void k_deform(const float* __restrict__ x,
                                                   const __half2* __restrict__ t4h,
                                                   const float* __restrict__ wdt2,
                                                   float* __restrict__ out) {
    int blk = blockIdx.x;
    int b = blk & 3;
    int strip = blk >> 2;         // 0..255
    int tid = threadIdx.x;
    int og = tid >> 4;            // 0..15 (4 out-channels each)
    int q = tid & 15;             // quad in strip
    int po0 = strip * 16;
    int qy = po0 >> 6;            // strip lies in one quad-row
    int qx0 = po0 & 63;

    __shared__ __align__(16) float vlds[2][16 * VP];  // 37376 B

    float acc[4][4];
    #pragma unroll
    for (int o = 0; o < 4; ++o)
        #pragma unroll
        for (int s = 0; s < 4; ++s) acc[o][s] = 0.f;

    const float* xb = x + (size_t)b * 64 * HX * WX;
    const __half2* osrc = t4h + (size_t)(b * 256 + strip) * 9216;

    for (int sup = 0; sup < 4; ++sup) {       // 2 chunks per super-iteration
        __syncthreads();          // prev phase2 done with vlds
        // hoisted offset loads: 2304 tasks = 9 full iters; 256B/wave contiguous
        __half2 o2h[9];
        #pragma unroll
        for (int it = 0; it < 9; ++it)
            o2h[it] = osrc[sup * 2304 + it * 256 + tid];

        // ---- phase 1 in 3 batches of 3 tasks: issue 27 gathers, then 3 tails
        #pragma unroll
        for (int g = 0; g < 3; ++g) {
            float tap[3][9];
            int y0a[3], x0a[3];
            float fya[3], fxa[3];
            #pragma unroll
            for (int j = 0; j < 3; ++j) {
                int it = g * 3 + j;
                int idx = it * 256 + tid;         // 0..2303
                int rowg = idx >> 4;              // 0..143
                int tq = idx & 15;
                int lc = rowg >= 72;
                int ckk = rowg - 72 * lc;         // 0..71 = ch*9+kk
                int ch = (ckk * 57) >> 9;         // /9
                int kk = ckk - ch * 9;
                int c = (sup * 2 + lc) * 8 + ch;
                float2 off = __half22float2(o2h[it]);
                float py = off.x + (float)(2 * qy + kk / 3);
                float px = off.y + (float)(2 * (qx0 + tq) + kk % 3);
                float y0f = floorf(py), x0f = floorf(px);
                fya[j] = py - y0f;
                fxa[j] = px - x0f;
                int y0 = (int)y0f, x0 = (int)x0f;
                y0a[j] = y0;
                x0a[j] = x0;
                const float* xp = xb + (size_t)c * (HX * WX);
                #pragma unroll
                for (int r = 0; r < 3; ++r) {
                    int yc = min(max(y0 + r, 0), HX - 1);
                    const float* rp = xp + yc * WX;
                    #pragma unroll
                    for (int sx = 0; sx < 3; ++sx) {
                        int xc = min(max(x0 + sx, 0), WX - 1);
                        tap[j][r * 3 + sx] = rp[xc];
                    }
                }
            }
            #pragma unroll
            for (int j = 0; j < 3; ++j) {
                int it = g * 3 + j;
                int idx = it * 256 + tid;
                int rowg = idx >> 4;
                int tq = idx & 15;
                int lc = rowg >= 72;
                int ckk = rowg - 72 * lc;
                int y0 = y0a[j], x0 = x0a[j];
                float fy = fya[j], fx = fxa[j];
                float t[9];
                #pragma unroll
                for (int r = 0; r < 3; ++r) {
                    int yy = y0 + r;
                    bool vy = (yy >= 0) & (yy < HX);
                    #pragma unroll
                    for (int sx = 0; sx < 3; ++sx) {
                        int xx = x0 + sx;
                        bool vx = (xx >= 0) & (xx < WX);
                        t[r * 3 + sx] = (vy & vx) ? tap[j][r * 3 + sx] : 0.f;
                    }
                }
                float h0[3], h1[3];
                #pragma unroll
                for (int r = 0; r < 3; ++r) {
                    h0[r] = t[r * 3 + 0] + fx * (t[r * 3 + 1] - t[r * 3 + 0]);
                    h1[r] = t[r * 3 + 1] + fx * (t[r * 3 + 2] - t[r * 3 + 1]);
                }
                float4 vv;
                vv.x = h0[0] + fy * (h0[1] - h0[0]);   // sub (0,0)
                vv.y = h1[0] + fy * (h1[1] - h1[0]);   // sub (0,1)
                vv.z = h0[1] + fy * (h0[2] - h0[1]);   // sub (1,0)
                vv.w = h1[1] + fy * (h1[2] - h1[1]);   // sub (1,1)
                *(float4*)&vlds[lc][tq * VP + ckk * 4] = vv;
            }
        }
        __syncthreads();          // vlds visible

        // ---- phase 2: acc[4 outs][4 sub] += w * v  (16 FMA per b128 read)
        #pragma unroll 1
        for (int lc = 0; lc < 2; ++lc) {
            for (int ch = 0; ch < 8; ++ch) {
                int c = (sup * 2 + lc) * 8 + ch;
                const float* wp = wdt2 + (size_t)(c * 9) * 64 + og * 4;
                const float* vp = &vlds[lc][q * VP + (ch * 9) * 4];
                #pragma unroll
                for (int k = 0; k < 9; ++k) {
                    float4 vv = *(const float4*)(vp + k * 4);
                    float4 w4 = *(const float4*)(wp + k * 64);
                    float wv[4] = {w4.x, w4.y, w4.z, w4.w};
                    #pragma unroll
                    for (int o = 0; o < 4; ++o) {
                        acc[o][0] += wv[o] * vv.x;
                        acc[o][1] += wv[o] * vv.y;
                        acc[o][2] += wv[o] * vv.z;
                        acc[o][3] += wv[o] * vv.w;
                    }
                }
            }
        }
    }
    // ---- epilogue
    int ho = 2 * qy, wo = 2 * (qx0 + q);
    #pragma unroll
    for (int o = 0; o < 4; ++o) {
        int oc = og * 4 + o;
        float* op = out + (((size_t)b * 64 + oc) * 128 + ho) * 128 + wo;
        *(float2*)op = make_float2(acc[o][0], acc[o][1]);
        *(float2*)(op + 128) = make_float2(acc[o][2], acc[o][3]);
    }
}

extern "C" void kernel_launch(void* const* d_in, const int* in_sizes, int n_in,
                              void* d_out, int out_size, void* d_ws, size_t ws_size,
                              hipStream_t stream) {
    const float* x  = (const float*)d_in[0];
    const float* w0 = (const float*)d_in[1];
    const float* b0 = (const float*)d_in[2];
    const float* w1 = (const float*)d_in[3];
    const float* b1 = (const float*)d_in[4];
    const float* w2 = (const float*)d_in[5];
    const float* b2 = (const float*)d_in[6];
    const float* w3 = (const float*)d_in[7];
    const float* b3 = (const float*)d_in[8];
    const float* wd = (const float*)d_in[9];
    float* out = (float*)d_out;

    float* ws = (float*)d_ws;
    float* p1    = ws;                       // 1,048,576 floats
    float* t2    = p1 + 1048576;             //   524,288
    float* t3    = t2 + 524288;              //   524,288
    __half2* t4h = (__half2*)(t3 + 524288);  // 9,437,184 half2 (37.7 MB)
    float* wdt2  = (float*)(t4h + 9437184);  //    36,864 floats

    k_wdt<<<144, 256, 0, stream>>>(wd, wdt2);
    k_conv0_pool<<<1024, 256, 0, stream>>>(x, w0, b0, p1);
    k_conv1x1_a<<<1024, 256, 0, stream>>>(p1, w1, b1, t2);
    k_conv3x3_b<<<1024, 256, 0, stream>>>(t2, w2, b2, t3);
    k_conv1x1_off<<<4608, 256, 0, stream>>>(t3, w3, b3, t4h);
    k_deform<<<1024, 256, 0, stream>>>(x, t4h, wdt2, out);
}